// Round 7
// baseline (433.782 us; speedup 1.0000x reference)
//
#include <hip/hip_runtime.h>
#include <hip/hip_bf16.h>

namespace {

constexpr int kB = 8192;   // batch
constexpr int kH = 1024;   // hidden
constexpr int kK = 2048;   // H + I
constexpr int kG = 4 * kH; // 4096 gate cols

typedef float f32x4 __attribute__((ext_vector_type(4)));
typedef unsigned short u16x8 __attribute__((ext_vector_type(8)));
typedef unsigned short u16x4 __attribute__((ext_vector_type(4)));

__device__ __forceinline__ unsigned short f2bf(float f) {
  return __builtin_bit_cast(unsigned short, __float2bfloat16(f));
}
__device__ __forceinline__ float sigmoidf_(float x) {
  return 1.0f / (1.0f + __expf(-x));
}
__device__ __forceinline__ u16x4 pack4(const float4 v) {
  return u16x4{f2bf(v.x), f2bf(v.y), f2bf(v.z), f2bf(v.w)};
}

// ---------------- Pass 1 (v3): coalesced pack f32 -> bf16 fragment-order tiles ----
// Packed tile (8192 shorts = 128 rows x 64 k):
//   off = mb*1024 + kb*512 + lh*128 + r15*8 + e  <->  row = mb*16+r15, k = kb*32+lh*8+e
__global__ __launch_bounds__(256) void prep_pack(
    const float* __restrict__ input, const float* __restrict__ weights,
    const float* __restrict__ bias, const float* __restrict__ old_h,
    unsigned short* __restrict__ Aw, unsigned short* __restrict__ Ww,
    float* __restrict__ bias_i) {
  const int b = blockIdx.x;
  const int tid = threadIdx.x;

  if (b >= 768) {  // bias interleave: 2 blocks x 256 threads x 8
    const int base = (b - 768) * 2048 + tid * 8;
    #pragma unroll
    for (int e = 0; e < 8; ++e) {
      const int j = base + e;
      bias_i[j] = bias[(j & 3) * kH + (j >> 2)];
    }
    return;
  }

  __shared__ unsigned short lbuf[128 * 280];  // 70 KB, row stride 280 shorts

  const int wid = tid >> 6, lane = tid & 63;
  const bool isW = (b >= 512);
  const int blk = isW ? (b - 512) : b;
  const int rb = blk >> 3;    // row-block: A 0..63, W 0..31
  const int kc = blk & 7;     // 256-col chunk

  #pragma unroll
  for (int io = 0; io < 4; ++io) {
    float4 v[8];
    #pragma unroll
    for (int ii = 0; ii < 8; ++ii) {
      const int row = (io * 8 + ii) * 4 + wid;
      const float* base;
      if (!isW) {
        const long rowg = (long)rb * 128 + row;
        base = (kc < 4) ? (old_h + rowg * kH + kc * 256)
                        : (input + rowg * kH + (kc * 256 - kH));
      } else {
        const int j = rb * 128 + row;
        const int g = j & 3, h = j >> 2;
        base = weights + ((long)g * kH + h) * kK + kc * 256;
      }
      v[ii] = ((const float4*)base)[lane];
    }
    #pragma unroll
    for (int ii = 0; ii < 8; ++ii) {
      const int row = (io * 8 + ii) * 4 + wid;
      *(u16x4*)&lbuf[row * 280 + lane * 4] = pack4(v[ii]);
    }
  }
  __syncthreads();

  unsigned short* dst = (isW ? Ww : Aw) + ((long)rb * 32 + kc * 4) * 8192;
  #pragma unroll
  for (int it = 0; it < 16; ++it) {
    const int o = (it * 256 + tid) * 8;
    const int oo = o & 8191;
    const int tl = o >> 13;
    const int r15 = (oo >> 3) & 15;
    const int lh = (oo >> 7) & 3;
    const int kb = (oo >> 9) & 1;
    const int mb = oo >> 10;
    const int row = mb * 16 + r15;
    const int cs = tl * 64 + kb * 32 + lh * 8;
    *(u16x8*)(dst + o) = *(const u16x8*)&lbuf[row * 280 + cs];
  }
}

// ---------------- Pass 2: 256x256 GEMM, 4-buffer BK=32 counted-vmcnt pipeline ----
// 8 waves (2Mx4N), per-wave 128x64 = acc[8][4]. 64 K-tiles of BK=32.
// LDS: 4 buffers x (A 8192 + B 8192 shorts) = 128 KB. Per tile: 4 global_load_lds
// (one per half-tile, linear dest). Pipeline 3 tiles deep; vmcnt(8) steady state
// (never 0); raw s_barrier (no drain); setprio around MFMA cluster.
// Per-tile LDS layout: A[half(2)][mb(8)][lane(64)][8], same for B.
__global__ __launch_bounds__(512, 2) void sublstm_gemm(
    const unsigned short* __restrict__ Aw, const unsigned short* __restrict__ Ww,
    const float* __restrict__ bias_i, const float* __restrict__ old_cell,
    float* __restrict__ out) {

  __shared__ union SM {
    unsigned short buf[4][16384];   // [buffer][A 8192 | B 8192]
    float Gc[32][260];              // epilogue overlay (first 33 KB)
  } sm;
  __shared__ float bias_s[256];

  const int tid  = threadIdx.x;
  const int lane = tid & 63;
  const int wid  = tid >> 6;
  const int wr   = wid >> 2;   // 0..1 (row half, 128 rows)
  const int wc   = wid & 3;    // 0..3 (64-col slice)

  // XCD swizzle: per-XCD walk in {2 A-panels + 2 W-panels} = 4MB L2 working set
  const int bid = blockIdx.x;                 // 0..511
  const int swz = (bid & 7) * 64 + (bid >> 3);
  const int xc  = swz >> 6;
  const int i6  = swz & 63;
  const int bm  = (i6 >> 2) * 2 + (i6 & 1);   // 0..31
  const int hb  = xc * 2 + ((i6 >> 1) & 1);   // 0..15

  // wave-uniform bias load (keeps per-wave vmcnt counts identical)
  bias_s[tid & 255] = bias_i[hb * 256 + (tid & 255)];

  const int soff = (tid >> 6) * 1024 + (tid & 63) * 8;  // source: mb*1024 + lane*8
  const int doff = tid * 8;                             // dest: linear
  const int aoff = wr * 4096 + lane * 8;
  const int bboff = (wc >> 1) * 4096 + (wc & 1) * 2048 + lane * 8;

  f32x4 acc[8][4];
  #pragma unroll
  for (int m = 0; m < 8; ++m)
    #pragma unroll
    for (int n = 0; n < 4; ++n)
      acc[m][n] = f32x4{0.f, 0.f, 0.f, 0.f};

#define BAR() __builtin_amdgcn_s_barrier()
#define VMCNT(N) asm volatile("s_waitcnt vmcnt(" #N ")" ::: "memory")

// Stage BK=32 K-tile T into buffer J: 4 half-tile loads, each one instruction/wave.
#define STAGE(J, T) do {                                                           \
    _Pragma("unroll")                                                              \
    for (int h_ = 0; h_ < 2; ++h_) {                                               \
      __builtin_amdgcn_global_load_lds(                                            \
          (const __attribute__((address_space(1))) unsigned int*)(                 \
              Aw + ((long)((2 * bm + h_) * 32 + ((T) >> 1))) * 8192                \
                 + ((T) & 1) * 512 + soff),                                        \
          (__attribute__((address_space(3))) unsigned int*)(&sm.buf[J][h_ * 4096 + doff]), \
          16, 0, 0);                                                               \
      __builtin_amdgcn_global_load_lds(                                            \
          (const __attribute__((address_space(1))) unsigned int*)(                 \
              Ww + ((long)((2 * hb + h_) * 32 + ((T) >> 1))) * 8192                \
                 + ((T) & 1) * 512 + soff),                                        \
          (__attribute__((address_space(3))) unsigned int*)(&sm.buf[J][8192 + h_ * 4096 + doff]), \
          16, 0, 0);                                                               \
    }                                                                              \
  } while (0)

// Compute one BK=32 tile from buffer J: 12 ds_read_b128 + 32 MFMA.
#define COMPUTE(J) do {                                                            \
    u16x8 bf_[4];                                                                  \
    _Pragma("unroll")                                                              \
    for (int n_ = 0; n_ < 4; ++n_)                                                 \
      bf_[n_] = *(const u16x8*)&sm.buf[J][8192 + bboff + n_ * 512];                \
    __builtin_amdgcn_s_setprio(1);                                                 \
    _Pragma("unroll")                                                              \
    for (int m_ = 0; m_ < 8; ++m_) {                                               \
      u16x8 af_ = *(const u16x8*)&sm.buf[J][aoff + m_ * 512];                      \
      _Pragma("unroll")                                                            \
      for (int n_ = 0; n_ < 4; ++n_)                                               \
        asm("v_mfma_f32_16x16x32_bf16 %0, %1, %2, %0"                              \
            : "+v"(acc[m_][n_]) : "v"(af_), "v"(bf_[n_]));                         \
    }                                                                              \
    __builtin_amdgcn_s_setprio(0);                                                 \
  } while (0)

  // prologue: 3 tiles in flight
  STAGE(0, 0); STAGE(1, 1); STAGE(2, 2);

  // steady state: tiles 0..59 (vmcnt(8) waits current tile, leaves 2 in flight)
  for (int i = 0; i < 15; ++i) {
    const int t = i * 4;
    VMCNT(8); BAR(); COMPUTE(0); BAR(); STAGE(3, t + 3);
    VMCNT(8); BAR(); COMPUTE(1); BAR(); STAGE(0, t + 4);
    VMCNT(8); BAR(); COMPUTE(2); BAR(); STAGE(1, t + 5);
    VMCNT(8); BAR(); COMPUTE(3); BAR(); STAGE(2, t + 6);
  }
  // tail: tiles 60..63, drain 8 -> 4 -> 0
  VMCNT(8); BAR(); COMPUTE(0); BAR(); STAGE(3, 63);
  VMCNT(8); BAR(); COMPUTE(1); BAR();
  VMCNT(4); BAR(); COMPUTE(2); BAR();
  VMCNT(0); BAR();

  // prefetch epilogue chunk 0's old_cell (overlaps last compute)
  float cnx[4];
  #pragma unroll
  for (int q = 0; q < 4; ++q) {
    const int grow = bm * 256 + q * 8 + wid;
    cnx[q] = old_cell[(long)grow * kH + hb * 64 + lane];
  }

  COMPUTE(3);

#undef STAGE
#undef COMPUTE
#undef VMCNT
#undef BAR

  // ---- fused epilogue: 8 chunks of 32 rows x 256 gate cols ----
  float* out_h = out;
  float* out_c = out + (long)kB * kH;

  #pragma unroll
  for (int c = 0; c < 8; ++c) {
    const int wrc = c >> 2, mm = c & 3;
    __syncthreads();  // previous chunk consumed / K-loop ds_reads retired
    if (wr == wrc) {
      #pragma unroll
      for (int m2 = 0; m2 < 2; ++m2)
        #pragma unroll
        for (int n = 0; n < 4; ++n) {
          const int col = wc * 64 + n * 16 + (lane & 15);   // C/D col = lane&15
          const int rb_ = m2 * 16 + (lane >> 4) * 4;        // row=(lane>>4)*4+j
          #pragma unroll
          for (int j = 0; j < 4; ++j)
            sm.Gc[rb_ + j][col] = acc[mm * 2 + m2][n][j];
        }
    }
    __syncthreads();

    float cc[4];
    #pragma unroll
    for (int q = 0; q < 4; ++q) cc[q] = cnx[q];
    if (c < 7) {  // prefetch next chunk's cells
      const int c2 = c + 1;
      #pragma unroll
      for (int q = 0; q < 4; ++q) {
        const int grow = bm * 256 + (c2 >> 2) * 128 + (c2 & 3) * 32 + q * 8 + wid;
        cnx[q] = old_cell[(long)grow * kH + hb * 64 + lane];
      }
    }

    #pragma unroll
    for (int q = 0; q < 4; ++q) {
      const int r = q * 8 + wid;            // chunk row 0..31
      const float4 gv = *(const float4*)&sm.Gc[r][lane * 4];  // i,o,z,f
      const float4 bv = *(const float4*)&bias_s[lane * 4];
      const float gi = sigmoidf_(gv.x + bv.x);
      const float go = sigmoidf_(gv.y + bv.y);
      const float gz = sigmoidf_(gv.z + bv.z);
      const float gf = sigmoidf_(gv.w + bv.w);
      const int grow = bm * 256 + wrc * 128 + mm * 32 + r;
      const long off = (long)grow * kH + hb * 64 + lane;
      const float nc = cc[q] * gf + gz - gi;
      out_h[off] = sigmoidf_(nc) - go;
      out_c[off] = nc;
    }
  }
}

// ---------------- Fallback (round-1 fused kernel) if ws too small ----------------
constexpr int FBM = 128, FBH = 32, FBN = 128, FBK = 32, FNKT = kK / FBK;

__device__ __forceinline__ u16x8 pack8f(const float4 v0, const float4 v1) {
  return u16x8{f2bf(v0.x), f2bf(v0.y), f2bf(v0.z), f2bf(v0.w),
               f2bf(v1.x), f2bf(v1.y), f2bf(v1.z), f2bf(v1.w)};
}

__global__ __launch_bounds__(256, 2) void sublstm_fused(
    const float* __restrict__ input, const float* __restrict__ weights,
    const float* __restrict__ bias, const float* __restrict__ old_h,
    const float* __restrict__ old_cell, float* __restrict__ out) {
  __shared__ unsigned short As[FBM][FBK + 8];
  __shared__ unsigned short Bs[FBN][FBK + 8];
  __shared__ float Gc[32][FBN + 4];

  const int tid = threadIdx.x, lane = tid & 63, wid = tid >> 6;
  const int wr = wid >> 1, wc = wid & 1;
  const int bid = blockIdx.x;
  const int bm = bid & 63, hh0 = (bid >> 6) * FBH;

  const int ra = tid >> 1, ca = (tid & 1) << 4;
  const long arow = (long)bm * FBM + ra;
  const int wrow = (ra >> 5) * kH + hh0 + (ra & 31);
  const float* abase_h = old_h + arow * kH + ca;
  const float* abase_x = input + arow * kH + ca - kH;
  const float* wbase = weights + (long)wrow * kK + ca;

  const int fr = lane & 15, ks = (lane >> 4) << 3;
  f32x4 acc[4][4];
  #pragma unroll
  for (int m = 0; m < 4; ++m)
    #pragma unroll
    for (int n = 0; n < 4; ++n) acc[m][n] = f32x4{0.f, 0.f, 0.f, 0.f};

  float4 a0, a1, a2, a3, b0, b1, b2, b3;
  {
    const float4* ap4 = (const float4*)abase_h;
    const float4* wp4 = (const float4*)wbase;
    a0 = ap4[0]; a1 = ap4[1]; a2 = ap4[2]; a3 = ap4[3];
    b0 = wp4[0]; b1 = wp4[1]; b2 = wp4[2]; b3 = wp4[3];
  }
  for (int kt = 0; kt < FNKT; ++kt) {
    u16x8 pa0 = pack8f(a0, a1), pa1 = pack8f(a2, a3);
    u16x8 pb0 = pack8f(b0, b1), pb1 = pack8f(b2, b3);
    __syncthreads();
    *(u16x8*)&As[ra][ca] = pa0; *(u16x8*)&As[ra][ca + 8] = pa1;
    *(u16x8*)&Bs[ra][ca] = pb0; *(u16x8*)&Bs[ra][ca + 8] = pb1;
    __syncthreads();
    if (kt + 1 < FNKT) {
      const int k0n = (kt + 1) * FBK;
      const float* ap = (k0n < kH) ? (abase_h + k0n) : (abase_x + k0n);
      const float4* ap4 = (const float4*)ap;
      const float4* wp4 = (const float4*)(wbase + k0n);
      a0 = ap4[0]; a1 = ap4[1]; a2 = ap4[2]; a3 = ap4[3];
      b0 = wp4[0]; b1 = wp4[1]; b2 = wp4[2]; b3 = wp4[3];
    }
    u16x8 af[4], bfv[4];
    #pragma unroll
    for (int m = 0; m < 4; ++m) af[m] = *(const u16x8*)&As[wr * 64 + m * 16 + fr][ks];
    #pragma unroll
    for (int n = 0; n < 4; ++n) bfv[n] = *(const u16x8*)&Bs[wc * 64 + n * 16 + fr][ks];
    #pragma unroll
    for (int m = 0; m < 4; ++m)
      #pragma unroll
      for (int n = 0; n < 4; ++n)
        asm("v_mfma_f32_16x16x32_bf16 %0, %1, %2, %0"
            : "+v"(acc[m][n]) : "v"(af[m]), "v"(bfv[n]));
  }
  float* out_h = out;
  float* out_c = out + (long)kB * kH;
  #pragma unroll
  for (int m = 0; m < 4; ++m) {
    __syncthreads();
    #pragma unroll
    for (int n = 0; n < 4; ++n) {
      const int col = wc * 64 + n * 16 + fr;
      #pragma unroll
      for (int j = 0; j < 4; ++j)
        Gc[wr * 16 + (lane >> 4) * 4 + j][col] = acc[m][n][j];
    }
    __syncthreads();
    #pragma unroll
    for (int q = 0; q < 4; ++q) {
      const int idx = tid + (q << 8);
      const int r = idx >> 5, h = idx & 31;
      const int hg = hh0 + h;
      const float gi = sigmoidf_(Gc[r][h] + bias[hg]);
      const float go = sigmoidf_(Gc[r][32 + h] + bias[kH + hg]);
      const float gz = sigmoidf_(Gc[r][64 + h] + bias[2 * kH + hg]);
      const float gf = sigmoidf_(Gc[r][96 + h] + bias[3 * kH + hg]);
      const int grow = bm * FBM + (r >> 4) * 64 + m * 16 + (r & 15);
      const long off = (long)grow * kH + hg;
      const float oc = old_cell[off];
      const float nc = oc * gf + gz - gi;
      out_h[off] = sigmoidf_(nc) - go;
      out_c[off] = nc;
    }
  }
}

}  // namespace

extern "C" void kernel_launch(void* const* d_in, const int* in_sizes, int n_in,
                              void* d_out, int out_size, void* d_ws, size_t ws_size,
                              hipStream_t stream) {
  const float* input    = (const float*)d_in[0];
  const float* weights  = (const float*)d_in[1];
  const float* bias     = (const float*)d_in[2];
  const float* old_h    = (const float*)d_in[3];
  const float* old_cell = (const float*)d_in[4];
  float* out = (float*)d_out;

  const size_t needA = (size_t)kB * kK * 2;      // 32 MB
  const size_t needW = (size_t)kG * kK * 2;      // 16 MB
  const size_t needBias = (size_t)kG * 4;        // 16 KB

  if (ws_size >= needA + needW + needBias) {
    unsigned short* Aw = (unsigned short*)d_ws;
    unsigned short* Ww = (unsigned short*)((char*)d_ws + needA);
    float* bias_i = (float*)((char*)d_ws + needA + needW);
    prep_pack<<<dim3(770), dim3(256), 0, stream>>>(input, weights, bias, old_h,
                                                   Aw, Ww, bias_i);
    sublstm_gemm<<<dim3(512), dim3(512), 0, stream>>>(Aw, Ww, bias_i, old_cell, out);
  } else {
    sublstm_fused<<<dim3(2048), dim3(256), 0, stream>>>(input, weights, bias, old_h,
                                                        old_cell, out);
  }
}